// Round 1
// baseline (1650.237 us; speedup 1.0000x reference)
//
#include <hip/hip_runtime.h>
#include <cstdint>

typedef unsigned long long u64;
typedef unsigned int u32;

#define NB 8
#define NP 4096
#define NK 64
#define NM 1024
#define NF 64
#define NOUT 128
#define R2C 0.04f      // float(0.2*0.2 in double) == 0x3D23D70A
#define CAP 2048

// Exact (non-contracted) squared distance, left-to-right sum, matching XLA's
// elementwise (a-b)**2 then reduce over the size-3 axis.
static __device__ __forceinline__ float sq3(float ax, float ay, float az,
                                            float bx, float by, float bz) {
  float dx = __fsub_rn(ax, bx), dy = __fsub_rn(ay, by), dz = __fsub_rn(az, bz);
  return __fadd_rn(__fadd_rn(__fmul_rn(dx, dx), __fmul_rn(dy, dy)), __fmul_rn(dz, dz));
}

// ---- kernel 0: transpose weights into ws (ch-major rows -> uniform s_load) ----
__global__ void prep_weights(const float* __restrict__ W1, const float* __restrict__ W2,
                             const float* __restrict__ W3,
                             float* __restrict__ w1t, float* __restrict__ w2t,
                             float* __restrict__ w3t) {
  int t = blockIdx.x * blockDim.x + threadIdx.x;
  int stride = gridDim.x * blockDim.x;
  for (int idx = t; idx < 64 * 67; idx += stride) {
    int ch = idx / 67, i = idx - ch * 67;
    w1t[idx] = W1[i * 64 + ch];
  }
  for (int idx = t; idx < 64 * 64; idx += stride) {
    int ch = idx >> 6, i = idx & 63;
    w2t[idx] = W2[i * 64 + ch];
  }
  for (int idx = t; idx < 128 * 64; idx += stride) {
    int ch = idx >> 6, i = idx & 63;
    w3t[idx] = W3[i * 128 + ch];
  }
}

// ---- kernel 1: farthest point sampling, one block per cloud ----
__global__ __launch_bounds__(1024) void fps_kernel(const float* __restrict__ pos,
                                                   float* __restrict__ selpos_ws,
                                                   float* __restrict__ out_selpos,
                                                   float* __restrict__ out_selbatch) {
  __shared__ float px[NP], py[NP], pz[NP];
  __shared__ u64 red[2][16];
  const int b = blockIdx.x, tid = threadIdx.x;
  const float* pb = pos + (size_t)b * NP * 3;
  for (int i = tid; i < NP; i += 1024) {
    px[i] = pb[i * 3];
    py[i] = pb[i * 3 + 1];
    pz[i] = pb[i * 3 + 2];
  }
  __syncthreads();
  float mx[4], my[4], mz[4], d[4];
  const float p0x = px[0], p0y = py[0], p0z = pz[0];
#pragma unroll
  for (int q = 0; q < 4; q++) {
    int i = tid + q * 1024;
    mx[q] = px[i]; my[q] = py[i]; mz[q] = pz[i];
    d[q] = sq3(mx[q], my[q], mz[q], p0x, p0y, p0z);
  }
  if (tid == 0) {
    int o = b * NM * 3;
    selpos_ws[o] = p0x; selpos_ws[o + 1] = p0y; selpos_ws[o + 2] = p0z;
    out_selpos[o] = p0x; out_selpos[o + 1] = p0y; out_selpos[o + 2] = p0z;
  }
  for (int m = tid; m < NM; m += 1024) out_selbatch[b * NM + m] = (float)b;

  const int lane = tid & 63, wid = tid >> 6;
  for (int m = 1; m < NM; m++) {
    // argmax over d with first-index tie-break: key = (bits(d)<<32) | (N-1-idx)
    u64 k = 0;
#pragma unroll
    for (int q = 0; q < 4; q++) {
      u64 kq = ((u64)__float_as_uint(d[q]) << 32) | (u32)(NP - 1 - (tid + q * 1024));
      if (kq > k) k = kq;
    }
#pragma unroll
    for (int s = 1; s < 64; s <<= 1) {
      u64 o = __shfl_xor(k, s);
      if (o > k) k = o;
    }
    if (lane == 0) red[m & 1][wid] = k;
    __syncthreads();
    k = red[m & 1][lane & 15];
#pragma unroll
    for (int s = 1; s < 16; s <<= 1) {
      u64 o = __shfl_xor(k, s);
      if (o > k) k = o;
    }
    const int i = NP - 1 - (int)(k & 0xffffffffu);
    const float cx = px[i], cy = py[i], cz = pz[i];
    if (tid == 0) {
      int o = (b * NM + m) * 3;
      selpos_ws[o] = cx; selpos_ws[o + 1] = cy; selpos_ws[o + 2] = cz;
      out_selpos[o] = cx; out_selpos[o + 1] = cy; out_selpos[o + 2] = cz;
    }
#pragma unroll
    for (int q = 0; q < 4; q++)
      d[q] = fminf(d[q], sq3(mx[q], my[q], mz[q], cx, cy, cz));
  }
}

// ---- kernel 2: radius ball query + exact K-smallest selection ----
__global__ __launch_bounds__(256) void ball_kernel(const float* __restrict__ pos,
                                                   const float* __restrict__ selpos_ws,
                                                   int* __restrict__ nbrp,
                                                   int* __restrict__ cntp) {
  __shared__ u64 keys[CAP];
  __shared__ int scnt;
  const int bm = blockIdx.x, tid = threadIdx.x;
  const int b = bm >> 10;  // NM = 1024
  if (tid == 0) scnt = 0;
  __syncthreads();
  const float sx = selpos_ws[bm * 3], sy = selpos_ws[bm * 3 + 1], sz = selpos_ws[bm * 3 + 2];
  const float* pb = pos + (size_t)b * NP * 3;
  for (int i = tid; i < NP; i += 256) {
    float d2 = sq3(sx, sy, sz, pb[i * 3], pb[i * 3 + 1], pb[i * 3 + 2]);
    if (d2 <= R2C) {
      int s = atomicAdd(&scnt, 1);
      if (s < CAP) keys[s] = ((u64)__float_as_uint(d2) << 32) | (u32)i;
    }
  }
  __syncthreads();
  int C = scnt > CAP ? CAP : scnt;
  // exact rank selection: keys are unique (idx in low bits) -> ranks unique
  for (int s = tid; s < C; s += 256) {
    u64 k = keys[s];
    int r = 0;
    for (int j2 = 0; j2 < C; j2++) r += (keys[j2] < k) ? 1 : 0;
    if (r < NK) nbrp[bm * NK + r] = (int)(k & 0xffffffffu);
  }
  if (tid == 0) cntp[bm] = C < NK ? C : NK;
}

// ---- kernel 3: per-pair MLP (registers + scalar weights) + masked max pool ----
__global__ __launch_bounds__(64) void mlp_kernel(
    const float* __restrict__ x, const float* __restrict__ pos,
    const float* __restrict__ selpos_ws, const int* __restrict__ nbrp,
    const int* __restrict__ cntp, const float* __restrict__ w1t,
    const float* __restrict__ w2t, const float* __restrict__ w3t,
    const float* __restrict__ b1, const float* __restrict__ b2,
    const float* __restrict__ b3, float* __restrict__ out) {
  const int pm = blockIdx.x, lane = threadIdx.x;
  const int b = pm >> 10;
  const int c = cntp[pm];
  const bool valid = lane < c;
  const int j = valid ? nbrp[pm * NK + lane] : 0;

  const float* xr = x + ((size_t)b * NP + j) * NF;
  float h0[67];
#pragma unroll
  for (int f = 0; f < 16; f++) {
    const float4 v = *(const float4*)(xr + f * 4);
    h0[f * 4 + 0] = v.x; h0[f * 4 + 1] = v.y;
    h0[f * 4 + 2] = v.z; h0[f * 4 + 3] = v.w;
  }
  {
    const float sx = selpos_ws[pm * 3], sy = selpos_ws[pm * 3 + 1], sz = selpos_ws[pm * 3 + 2];
    const float* pr = pos + ((size_t)b * NP + j) * 3;
    h0[64] = pr[0] - sx; h0[65] = pr[1] - sy; h0[66] = pr[2] - sz;
  }
  float h1[64];
#pragma unroll
  for (int ch = 0; ch < 64; ch++) {
    float a = b1[ch];
    const float* w = w1t + ch * 67;
#pragma unroll
    for (int i2 = 0; i2 < 67; i2++) a = fmaf(h0[i2], w[i2], a);
    h1[ch] = fmaxf(a, 0.f);
  }
  float h2[64];
#pragma unroll
  for (int ch = 0; ch < 64; ch++) {
    float a = b2[ch];
    const float* w = w2t + ch * 64;
#pragma unroll
    for (int i2 = 0; i2 < 64; i2++) a = fmaf(h1[i2], w[i2], a);
    h2[ch] = fmaxf(a, 0.f);
  }
  float olo = 0.f, ohi = 0.f;
  for (int ch = 0; ch < 128; ch++) {  // rolled: scalar acc, no register array
    float a = b3[ch];
    const float* w = w3t + ch * 64;
#pragma unroll
    for (int i2 = 0; i2 < 64; i2++) a = fmaf(h2[i2], w[i2], a);
    a = fmaxf(a, 0.f);
    a = valid ? a : -__builtin_inff();
#pragma unroll
    for (int s2 = 1; s2 < 64; s2 <<= 1) a = fmaxf(a, __shfl_xor(a, s2));
    if ((ch & 63) == lane) {
      if (ch < 64) olo = a; else ohi = a;
    }
  }
  if (c == 0) { olo = 0.f; ohi = 0.f; }
  out[(size_t)pm * NOUT + lane] = olo;
  out[(size_t)pm * NOUT + 64 + lane] = ohi;
}

extern "C" void kernel_launch(void* const* d_in, const int* in_sizes, int n_in,
                              void* d_out, int out_size, void* d_ws, size_t ws_size,
                              hipStream_t stream) {
  const float* x   = (const float*)d_in[0];
  const float* pos = (const float*)d_in[1];
  // d_in[2] = batch (unused; reconstructed analytically)
  const float* W1 = (const float*)d_in[3];
  const float* b1 = (const float*)d_in[4];
  const float* W2 = (const float*)d_in[5];
  const float* b2 = (const float*)d_in[6];
  const float* W3 = (const float*)d_in[7];
  const float* b3 = (const float*)d_in[8];

  float* out         = (float*)d_out;
  float* out_selpos  = out + (size_t)NB * NM * NOUT;   // 1048576
  float* out_selbatch = out_selpos + (size_t)NB * NM * 3;  // +24576

  int* ws_i = (int*)d_ws;
  float* ws_f = (float*)d_ws;
  int* cntp    = ws_i + 8192;
  int* nbrp    = ws_i + 16384;
  float* selpos = ws_f + 540672;
  float* w1t   = ws_f + 565248;
  float* w2t   = ws_f + 569536;
  float* w3t   = ws_f + 573632;

  hipLaunchKernelGGL(prep_weights, dim3(34), dim3(256), 0, stream, W1, W2, W3, w1t, w2t, w3t);
  hipLaunchKernelGGL(fps_kernel, dim3(NB), dim3(1024), 0, stream, pos, selpos, out_selpos, out_selbatch);
  hipLaunchKernelGGL(ball_kernel, dim3(NB * NM), dim3(256), 0, stream, pos, selpos, nbrp, cntp);
  hipLaunchKernelGGL(mlp_kernel, dim3(NB * NM), dim3(64), 0, stream,
                     x, pos, selpos, nbrp, cntp, w1t, w2t, w3t, b1, b2, b3, out);
}

// Round 2
// 1249.053 us; speedup vs baseline: 1.3212x; 1.3212x over previous
//
#include <hip/hip_runtime.h>
#include <cstdint>

typedef unsigned long long u64;
typedef unsigned int u32;

#define NB 8
#define NP 4096
#define NK 64
#define NM 1024
#define NF 64
#define NOUT 128
#define R2C 0.04f      // float(0.2*0.2 in double) == 0x3D23D70A
#define CAP 2048
#define FPS_T 512
#define FPS_Q 8
#define MPAD 65

// Exact (non-contracted) squared distance, left-to-right sum, matching XLA's
// elementwise (a-b)**2 then reduce over the size-3 axis.
static __device__ __forceinline__ float sq3(float ax, float ay, float az,
                                            float bx, float by, float bz) {
  float dx = __fsub_rn(ax, bx), dy = __fsub_rn(ay, by), dz = __fsub_rn(az, bz);
  return __fadd_rn(__fadd_rn(__fmul_rn(dx, dx), __fmul_rn(dy, dy)), __fmul_rn(dz, dz));
}

// u64 max-combine with a DPP-shifted copy (VALU, ~4cyc vs ~120cyc ds_bpermute)
template <int CTRL>
static __device__ __forceinline__ u64 dpp_max_u64(u64 k) {
  u32 lo = (u32)k, hi = (u32)(k >> 32);
  u32 plo = (u32)__builtin_amdgcn_update_dpp(0, (int)lo, CTRL, 0xf, 0xf, true);
  u32 phi = (u32)__builtin_amdgcn_update_dpp(0, (int)hi, CTRL, 0xf, 0xf, true);
  u64 p = ((u64)phi << 32) | plo;
  return p > k ? p : k;
}

// ---- kernel 0: transpose weights into ws (ch-major rows -> uniform s_load) ----
__global__ void prep_weights(const float* __restrict__ W1, const float* __restrict__ W2,
                             const float* __restrict__ W3,
                             float* __restrict__ w1t, float* __restrict__ w2t,
                             float* __restrict__ w3t) {
  int t = blockIdx.x * blockDim.x + threadIdx.x;
  int stride = gridDim.x * blockDim.x;
  for (int idx = t; idx < 64 * 67; idx += stride) {
    int ch = idx / 67, i = idx - ch * 67;
    w1t[idx] = W1[i * 64 + ch];
  }
  for (int idx = t; idx < 64 * 64; idx += stride) {
    int ch = idx >> 6, i = idx & 63;
    w2t[idx] = W2[i * 64 + ch];
  }
  for (int idx = t; idx < 128 * 64; idx += stride) {
    int ch = idx >> 6, i = idx & 63;
    w3t[idx] = W3[i * 128 + ch];
  }
}

// ---- kernel 1: FPS — 512 thr, 8 reg-resident pts/lane, DPP reduce, 1 barrier/iter ----
__global__ __launch_bounds__(FPS_T) void fps_kernel(const float* __restrict__ pos,
                                                    float* __restrict__ selpos_ws,
                                                    float* __restrict__ out_selpos,
                                                    float* __restrict__ out_selbatch) {
  __shared__ float px[NP], py[NP], pz[NP];
  __shared__ u64 red[4];
  const int b = blockIdx.x, tid = threadIdx.x;
  const float* pb = pos + (size_t)b * NP * 3;
  for (int i = tid; i < NP; i += FPS_T) {
    px[i] = pb[i * 3]; py[i] = pb[i * 3 + 1]; pz[i] = pb[i * 3 + 2];
  }
  if (tid < 4) red[tid] = 0;
  for (int m = tid; m < NM; m += FPS_T) out_selbatch[b * NM + m] = (float)b;
  __syncthreads();

  float mx[FPS_Q], my[FPS_Q], mz[FPS_Q], d[FPS_Q];
  const float p0x = px[0], p0y = py[0], p0z = pz[0];
#pragma unroll
  for (int q = 0; q < FPS_Q; q++) {
    int p = tid * FPS_Q + q;
    mx[q] = px[p]; my[q] = py[p]; mz[q] = pz[p];
    d[q] = sq3(mx[q], my[q], mz[q], p0x, p0y, p0z);
  }
  if (tid == 0) {
    int o = b * NM * 3;
    selpos_ws[o] = p0x; selpos_ws[o + 1] = p0y; selpos_ws[o + 2] = p0z;
    out_selpos[o] = p0x; out_selpos[o + 1] = p0y; out_selpos[o + 2] = p0z;
  }
  const int lane = tid & 63;
  for (int m = 1; m < NM; m++) {
    // local argmax (strict > keeps lowest local q -> lowest global idx)
    float bd = d[0]; int bq = 0;
#pragma unroll
    for (int q = 1; q < FPS_Q; q++) {
      bool g = d[q] > bd;
      bd = g ? d[q] : bd; bq = g ? q : bq;
    }
    u64 k = ((u64)__float_as_uint(bd) << 32) | (u32)(NP - 1 - (tid * FPS_Q + bq));
    // wave reduce-to-lane63 via DPP: shr1,2,4,8 then bcast15, bcast31
    k = dpp_max_u64<0x111>(k);
    k = dpp_max_u64<0x112>(k);
    k = dpp_max_u64<0x114>(k);
    k = dpp_max_u64<0x118>(k);
    k = dpp_max_u64<0x142>(k);
    k = dpp_max_u64<0x143>(k);
    if (lane == 63) atomicMax(&red[m & 3], k);
    if (tid == 0) red[(m + 1) & 3] = 0;  // last read 3 iters ago; 2 barriers since
    __syncthreads();
    const u64 g = red[m & 3];
    const int i = NP - 1 - (int)(u32)g;
    const float cx = px[i], cy = py[i], cz = pz[i];
    if (tid == 0) {
      int o = (b * NM + m) * 3;
      selpos_ws[o] = cx; selpos_ws[o + 1] = cy; selpos_ws[o + 2] = cz;
      out_selpos[o] = cx; out_selpos[o + 1] = cy; out_selpos[o + 2] = cz;
    }
#pragma unroll
    for (int q = 0; q < FPS_Q; q++)
      d[q] = fminf(d[q], sq3(mx[q], my[q], mz[q], cx, cy, cz));
  }
}

// ---- kernel 2: radius ball query + exact K-smallest selection ----
__global__ __launch_bounds__(256) void ball_kernel(const float* __restrict__ pos,
                                                   const float* __restrict__ selpos_ws,
                                                   int* __restrict__ nbrp,
                                                   int* __restrict__ cntp) {
  __shared__ u64 keys[CAP];
  __shared__ int scnt;
  const int bm = blockIdx.x, tid = threadIdx.x;
  const int b = bm >> 10;  // NM = 1024
  if (tid == 0) scnt = 0;
  __syncthreads();
  const float sx = selpos_ws[bm * 3], sy = selpos_ws[bm * 3 + 1], sz = selpos_ws[bm * 3 + 2];
  const float* pb = pos + (size_t)b * NP * 3;
  for (int i = tid; i < NP; i += 256) {
    float d2 = sq3(sx, sy, sz, pb[i * 3], pb[i * 3 + 1], pb[i * 3 + 2]);
    if (d2 <= R2C) {
      int s = atomicAdd(&scnt, 1);
      if (s < CAP) keys[s] = ((u64)__float_as_uint(d2) << 32) | (u32)i;
    }
  }
  __syncthreads();
  int C = scnt > CAP ? CAP : scnt;
  // exact rank selection: keys are unique (idx in low bits) -> ranks unique
  for (int s = tid; s < C; s += 256) {
    u64 k = keys[s];
    int r = 0;
    for (int j2 = 0; j2 < C; j2++) r += (keys[j2] < k) ? 1 : 0;
    if (r < NK) nbrp[bm * NK + r] = (int)(k & 0xffffffffu);
  }
  if (tid == 0) cntp[bm] = C < NK ? C : NK;
}

// ---- kernel 3: MLP — block=256=4 waves per selected point; lane=neighbor,
//      wave=channel slice; uniform s_load weights; padded LDS exchange ----
__global__ __launch_bounds__(256) void mlp_kernel(
    const float* __restrict__ x, const float* __restrict__ pos,
    const float* __restrict__ selpos_ws, const int* __restrict__ nbrp,
    const int* __restrict__ cntp, const float* __restrict__ w1t,
    const float* __restrict__ w2t, const float* __restrict__ w3t,
    const float* __restrict__ b1, const float* __restrict__ b2,
    const float* __restrict__ b3, float* __restrict__ out) {
  __shared__ float hs[2 * 64 * MPAD];  // h1s=[64][65]; h2s=+64*65; h3 reuses all as [128][65]
  const int pm = blockIdx.x, tid = threadIdx.x;
  const int n = tid & 63;
  const int w = __builtin_amdgcn_readfirstlane(tid >> 6);  // wave-uniform -> SGPR
  const int b = pm >> 10;
  const int c = cntp[pm];
  const bool valid = n < c;
  const int j = valid ? nbrp[pm * NK + n] : 0;
  const float NEGINF = -__builtin_inff();

  float h0[67];
  const float* xr = x + ((size_t)b * NP + j) * NF;
#pragma unroll
  for (int f = 0; f < 16; f++) {
    const float4 v = *(const float4*)(xr + f * 4);
    h0[4 * f] = v.x; h0[4 * f + 1] = v.y; h0[4 * f + 2] = v.z; h0[4 * f + 3] = v.w;
  }
  {
    const float sx = selpos_ws[pm * 3], sy = selpos_ws[pm * 3 + 1], sz = selpos_ws[pm * 3 + 2];
    const float* pr = pos + ((size_t)b * NP + j) * 3;
    h0[64] = pr[0] - sx; h0[65] = pr[1] - sy; h0[66] = pr[2] - sz;
  }
  // layer 1: my 16 channels; scalar acc -> LDS immediately (no reg arrays)
  const int cb1 = w * 16;
  for (int cc = 0; cc < 16; ++cc) {
    const int ch = cb1 + cc;
    float a = b1[ch];
    const float* wr = w1t + ch * 67;
#pragma unroll
    for (int i = 0; i < 67; ++i) a = fmaf(h0[i], wr[i], a);
    hs[n * MPAD + ch] = fmaxf(a, 0.f);
  }
  __syncthreads();
  float h1r[64];
#pragma unroll
  for (int i = 0; i < 64; ++i) h1r[i] = hs[n * MPAD + i];
  // layer 2
  for (int cc = 0; cc < 16; ++cc) {
    const int ch = cb1 + cc;
    float a = b2[ch];
    const float* wr = w2t + ch * 64;
#pragma unroll
    for (int i = 0; i < 64; ++i) a = fmaf(h1r[i], wr[i], a);
    hs[64 * MPAD + n * MPAD + ch] = fmaxf(a, 0.f);
  }
  __syncthreads();
  float h2r[64];
#pragma unroll
  for (int i = 0; i < 64; ++i) h2r[i] = hs[64 * MPAD + n * MPAD + i];
  __syncthreads();  // everyone has h2 in regs before h3 overwrites hs
  // layer 3: my 32 channels -> h3[ch][n]
  const int cb3 = w * 32;
  for (int cc = 0; cc < 32; ++cc) {
    const int ch = cb3 + cc;
    float a = b3[ch];
    const float* wr = w3t + ch * 64;
#pragma unroll
    for (int i = 0; i < 64; ++i) a = fmaf(h2r[i], wr[i], a);
    a = fmaxf(a, 0.f);
    hs[ch * MPAD + n] = valid ? a : NEGINF;
  }
  __syncthreads();
  // pool: thread t<128 reduces channel t over 64 neighbors
  if (tid < 128) {
    float m0 = NEGINF;
#pragma unroll
    for (int i = 0; i < 64; ++i) m0 = fmaxf(m0, hs[tid * MPAD + i]);
    out[(size_t)pm * NOUT + tid] = (c == 0) ? 0.f : m0;
  }
}

extern "C" void kernel_launch(void* const* d_in, const int* in_sizes, int n_in,
                              void* d_out, int out_size, void* d_ws, size_t ws_size,
                              hipStream_t stream) {
  const float* x   = (const float*)d_in[0];
  const float* pos = (const float*)d_in[1];
  // d_in[2] = batch (unused; reconstructed analytically)
  const float* W1 = (const float*)d_in[3];
  const float* b1 = (const float*)d_in[4];
  const float* W2 = (const float*)d_in[5];
  const float* b2 = (const float*)d_in[6];
  const float* W3 = (const float*)d_in[7];
  const float* b3 = (const float*)d_in[8];

  float* out          = (float*)d_out;
  float* out_selpos   = out + (size_t)NB * NM * NOUT;      // 1048576
  float* out_selbatch = out_selpos + (size_t)NB * NM * 3;  // +24576

  int* ws_i = (int*)d_ws;
  float* ws_f = (float*)d_ws;
  int* cntp     = ws_i + 8192;
  int* nbrp     = ws_i + 16384;
  float* selpos = ws_f + 540672;
  float* w1t    = ws_f + 565248;
  float* w2t    = ws_f + 569536;
  float* w3t    = ws_f + 573632;

  hipLaunchKernelGGL(prep_weights, dim3(34), dim3(256), 0, stream, W1, W2, W3, w1t, w2t, w3t);
  hipLaunchKernelGGL(fps_kernel, dim3(NB), dim3(FPS_T), 0, stream, pos, selpos, out_selpos, out_selbatch);
  hipLaunchKernelGGL(ball_kernel, dim3(NB * NM), dim3(256), 0, stream, pos, selpos, nbrp, cntp);
  hipLaunchKernelGGL(mlp_kernel, dim3(NB * NM), dim3(256), 0, stream,
                     x, pos, selpos, nbrp, cntp, w1t, w2t, w3t, b1, b2, b3, out);
}

// Round 3
// 1241.106 us; speedup vs baseline: 1.3297x; 1.0064x over previous
//
#include <hip/hip_runtime.h>
#include <cstdint>

typedef unsigned long long u64;
typedef unsigned int u32;

#define NB 8
#define NP 4096
#define NK 64
#define NM 1024
#define NF 64
#define NOUT 128
#define R2C 0.04f      // float(0.2*0.2 in double) == 0x3D23D70A
#define CAP 2048
#define FPS_T 512
#define FPS_Q 8
#define MPAD 65

// Exact (non-contracted) squared distance, left-to-right sum, matching XLA's
// elementwise (a-b)**2 then reduce over the size-3 axis.
static __device__ __forceinline__ float sq3(float ax, float ay, float az,
                                            float bx, float by, float bz) {
  float dx = __fsub_rn(ax, bx), dy = __fsub_rn(ay, by), dz = __fsub_rn(az, bz);
  return __fadd_rn(__fadd_rn(__fmul_rn(dx, dx), __fmul_rn(dy, dy)), __fmul_rn(dz, dz));
}

// f32 max with a DPP-shifted copy; bound_ctrl=1 feeds 0.0f (safe: d2 >= 0)
template <int CTRL>
static __device__ __forceinline__ float dpp_maxf(float x) {
  int m = __builtin_amdgcn_update_dpp(0, __float_as_int(x), CTRL, 0xf, 0xf, true);
  return fmaxf(x, __int_as_float(m));
}

static __device__ __forceinline__ u64 umax64(u64 a, u64 b) { return a > b ? a : b; }

// ---- kernel 0: transpose weights into ws (ch-major rows -> uniform s_load) ----
__global__ void prep_weights(const float* __restrict__ W1, const float* __restrict__ W2,
                             const float* __restrict__ W3,
                             float* __restrict__ w1t, float* __restrict__ w2t,
                             float* __restrict__ w3t) {
  int t = blockIdx.x * blockDim.x + threadIdx.x;
  int stride = gridDim.x * blockDim.x;
  for (int idx = t; idx < 64 * 67; idx += stride) {
    int ch = idx / 67, i = idx - ch * 67;
    w1t[idx] = W1[i * 64 + ch];
  }
  for (int idx = t; idx < 64 * 64; idx += stride) {
    int ch = idx >> 6, i = idx & 63;
    w2t[idx] = W2[i * 64 + ch];
  }
  for (int idx = t; idx < 128 * 64; idx += stride) {
    int ch = idx >> 6, i = idx & 63;
    w3t[idx] = W3[i * 128 + ch];
  }
}

// ---- kernel 1: FPS — f32 DPP wave-reduce + ballot index recovery,
//      per-wave LDS slots (no atomics), 1 barrier/iter ----
__global__ __launch_bounds__(FPS_T) void fps_kernel(const float* __restrict__ pos,
                                                    float* __restrict__ selpos_ws,
                                                    float* __restrict__ out_selpos,
                                                    float* __restrict__ out_selbatch) {
  __shared__ float4 pxyz[NP];
  __shared__ u64 red[2][8];
  const int b = blockIdx.x, tid = threadIdx.x;
  const float* pb = pos + (size_t)b * NP * 3;
  for (int i = tid; i < NP; i += FPS_T)
    pxyz[i] = make_float4(pb[i * 3], pb[i * 3 + 1], pb[i * 3 + 2], 0.f);
  for (int m = tid; m < NM; m += FPS_T) out_selbatch[b * NM + m] = (float)b;
  __syncthreads();

  float mx[FPS_Q], my[FPS_Q], mz[FPS_Q], d[FPS_Q];
  const float4 p0 = pxyz[0];
#pragma unroll
  for (int q = 0; q < FPS_Q; q++) {
    const float4 P = pxyz[tid * FPS_Q + q];
    mx[q] = P.x; my[q] = P.y; mz[q] = P.z;
    d[q] = sq3(P.x, P.y, P.z, p0.x, p0.y, p0.z);
  }
  if (tid == 0) {
    int o = b * NM * 3;
    selpos_ws[o] = p0.x; selpos_ws[o + 1] = p0.y; selpos_ws[o + 2] = p0.z;
    out_selpos[o] = p0.x; out_selpos[o + 1] = p0.y; out_selpos[o + 2] = p0.z;
  }
  const int lane = tid & 63, w = tid >> 6;
  for (int m = 1; m < NM; m++) {
    // per-lane argmax over 8 (strict > keeps lowest q -> lowest global idx)
    float bd = d[0]; int bq = 0;
#pragma unroll
    for (int q = 1; q < FPS_Q; q++) {
      bool g = d[q] > bd;
      bd = g ? d[q] : bd; bq = g ? q : bq;
    }
    // wave max (f32): shr1,2,4,8 + bcast15 + bcast31 -> lane 63
    float wm = bd;
    wm = dpp_maxf<0x111>(wm);
    wm = dpp_maxf<0x112>(wm);
    wm = dpp_maxf<0x114>(wm);
    wm = dpp_maxf<0x118>(wm);
    wm = dpp_maxf<0x142>(wm);
    wm = dpp_maxf<0x143>(wm);
    const u32 wbits = (u32)__builtin_amdgcn_readlane(__float_as_int(wm), 63);
    const float wmax = __int_as_float((int)wbits);
    // lowest lane holding the max; its candidate idx (lane order == idx order)
    const u64 msk = __ballot(bd == wmax);
    const int fl = (int)__ffsll((long long)msk) - 1;
    const int il = __builtin_amdgcn_readlane(tid * FPS_Q + bq, fl);
    if (lane == 0)
      red[m & 1][w] = ((u64)wbits << 32) | (u32)(NP - 1 - il);
    __syncthreads();
    // all lanes: broadcast-read 8 slots, tree max
    const u64* rs = red[m & 1];
    u64 g = umax64(umax64(umax64(rs[0], rs[1]), umax64(rs[2], rs[3])),
                   umax64(umax64(rs[4], rs[5]), umax64(rs[6], rs[7])));
    const int i = NP - 1 - (int)(u32)g;
    const float4 P = pxyz[i];
    if (tid == 0) {
      int o = (b * NM + m) * 3;
      selpos_ws[o] = P.x; selpos_ws[o + 1] = P.y; selpos_ws[o + 2] = P.z;
      out_selpos[o] = P.x; out_selpos[o + 1] = P.y; out_selpos[o + 2] = P.z;
    }
#pragma unroll
    for (int q = 0; q < FPS_Q; q++)
      d[q] = fminf(d[q], sq3(mx[q], my[q], mz[q], P.x, P.y, P.z));
  }
}

// ---- kernel 2: radius ball query + exact K-smallest selection ----
__global__ __launch_bounds__(256) void ball_kernel(const float* __restrict__ pos,
                                                   const float* __restrict__ selpos_ws,
                                                   int* __restrict__ nbrp,
                                                   int* __restrict__ cntp) {
  __shared__ u64 keys[CAP];
  __shared__ int scnt;
  const int bm = blockIdx.x, tid = threadIdx.x;
  const int b = bm >> 10;  // NM = 1024
  if (tid == 0) scnt = 0;
  __syncthreads();
  const float sx = selpos_ws[bm * 3], sy = selpos_ws[bm * 3 + 1], sz = selpos_ws[bm * 3 + 2];
  const float* pb = pos + (size_t)b * NP * 3;
  for (int i = tid; i < NP; i += 256) {
    float d2 = sq3(sx, sy, sz, pb[i * 3], pb[i * 3 + 1], pb[i * 3 + 2]);
    if (d2 <= R2C) {
      int s = atomicAdd(&scnt, 1);
      if (s < CAP) keys[s] = ((u64)__float_as_uint(d2) << 32) | (u32)i;
    }
  }
  __syncthreads();
  int C = scnt > CAP ? CAP : scnt;
  // exact rank selection: keys are unique (idx in low bits) -> ranks unique
  for (int s = tid; s < C; s += 256) {
    u64 k = keys[s];
    int r = 0;
    for (int j2 = 0; j2 < C; j2++) r += (keys[j2] < k) ? 1 : 0;
    if (r < NK) nbrp[bm * NK + r] = (int)(k & 0xffffffffu);
  }
  if (tid == 0) cntp[bm] = C < NK ? C : NK;
}

// ---- kernel 3: MLP — block=256=4 waves per selected point; lane=neighbor,
//      wave=channel slice; uniform s_load weights; padded LDS exchange ----
__global__ __launch_bounds__(256) void mlp_kernel(
    const float* __restrict__ x, const float* __restrict__ pos,
    const float* __restrict__ selpos_ws, const int* __restrict__ nbrp,
    const int* __restrict__ cntp, const float* __restrict__ w1t,
    const float* __restrict__ w2t, const float* __restrict__ w3t,
    const float* __restrict__ b1, const float* __restrict__ b2,
    const float* __restrict__ b3, float* __restrict__ out) {
  __shared__ float hs[2 * 64 * MPAD];  // h1s=[64][65]; h2s=+64*65; h3 reuses all as [128][65]
  const int pm = blockIdx.x, tid = threadIdx.x;
  const int n = tid & 63;
  const int w = __builtin_amdgcn_readfirstlane(tid >> 6);  // wave-uniform -> SGPR
  const int b = pm >> 10;
  const int c = cntp[pm];
  const bool valid = n < c;
  const int j = valid ? nbrp[pm * NK + n] : 0;
  const float NEGINF = -__builtin_inff();

  float h0[67];
  const float* xr = x + ((size_t)b * NP + j) * NF;
#pragma unroll
  for (int f = 0; f < 16; f++) {
    const float4 v = *(const float4*)(xr + f * 4);
    h0[4 * f] = v.x; h0[4 * f + 1] = v.y; h0[4 * f + 2] = v.z; h0[4 * f + 3] = v.w;
  }
  {
    const float sx = selpos_ws[pm * 3], sy = selpos_ws[pm * 3 + 1], sz = selpos_ws[pm * 3 + 2];
    const float* pr = pos + ((size_t)b * NP + j) * 3;
    h0[64] = pr[0] - sx; h0[65] = pr[1] - sy; h0[66] = pr[2] - sz;
  }
  // layer 1: my 16 channels; scalar acc -> LDS immediately (no reg arrays)
  const int cb1 = w * 16;
  for (int cc = 0; cc < 16; ++cc) {
    const int ch = cb1 + cc;
    float a = b1[ch];
    const float* wr = w1t + ch * 67;
#pragma unroll
    for (int i = 0; i < 67; ++i) a = fmaf(h0[i], wr[i], a);
    hs[n * MPAD + ch] = fmaxf(a, 0.f);
  }
  __syncthreads();
  float h1r[64];
#pragma unroll
  for (int i = 0; i < 64; ++i) h1r[i] = hs[n * MPAD + i];
  // layer 2
  for (int cc = 0; cc < 16; ++cc) {
    const int ch = cb1 + cc;
    float a = b2[ch];
    const float* wr = w2t + ch * 64;
#pragma unroll
    for (int i = 0; i < 64; ++i) a = fmaf(h1r[i], wr[i], a);
    hs[64 * MPAD + n * MPAD + ch] = fmaxf(a, 0.f);
  }
  __syncthreads();
  float h2r[64];
#pragma unroll
  for (int i = 0; i < 64; ++i) h2r[i] = hs[64 * MPAD + n * MPAD + i];
  __syncthreads();  // everyone has h2 in regs before h3 overwrites hs
  // layer 3: my 32 channels -> h3[ch][n]
  const int cb3 = w * 32;
  for (int cc = 0; cc < 32; ++cc) {
    const int ch = cb3 + cc;
    float a = b3[ch];
    const float* wr = w3t + ch * 64;
#pragma unroll
    for (int i = 0; i < 64; ++i) a = fmaf(h2r[i], wr[i], a);
    a = fmaxf(a, 0.f);
    hs[ch * MPAD + n] = valid ? a : NEGINF;
  }
  __syncthreads();
  // pool: thread t<128 reduces channel t over 64 neighbors
  if (tid < 128) {
    float m0 = NEGINF;
#pragma unroll
    for (int i = 0; i < 64; ++i) m0 = fmaxf(m0, hs[tid * MPAD + i]);
    out[(size_t)pm * NOUT + tid] = (c == 0) ? 0.f : m0;
  }
}

extern "C" void kernel_launch(void* const* d_in, const int* in_sizes, int n_in,
                              void* d_out, int out_size, void* d_ws, size_t ws_size,
                              hipStream_t stream) {
  const float* x   = (const float*)d_in[0];
  const float* pos = (const float*)d_in[1];
  // d_in[2] = batch (unused; reconstructed analytically)
  const float* W1 = (const float*)d_in[3];
  const float* b1 = (const float*)d_in[4];
  const float* W2 = (const float*)d_in[5];
  const float* b2 = (const float*)d_in[6];
  const float* W3 = (const float*)d_in[7];
  const float* b3 = (const float*)d_in[8];

  float* out          = (float*)d_out;
  float* out_selpos   = out + (size_t)NB * NM * NOUT;      // 1048576
  float* out_selbatch = out_selpos + (size_t)NB * NM * 3;  // +24576

  int* ws_i = (int*)d_ws;
  float* ws_f = (float*)d_ws;
  int* cntp     = ws_i + 8192;
  int* nbrp     = ws_i + 16384;
  float* selpos = ws_f + 540672;
  float* w1t    = ws_f + 565248;
  float* w2t    = ws_f + 569536;
  float* w3t    = ws_f + 573632;

  hipLaunchKernelGGL(prep_weights, dim3(34), dim3(256), 0, stream, W1, W2, W3, w1t, w2t, w3t);
  hipLaunchKernelGGL(fps_kernel, dim3(NB), dim3(FPS_T), 0, stream, pos, selpos, out_selpos, out_selbatch);
  hipLaunchKernelGGL(ball_kernel, dim3(NB * NM), dim3(256), 0, stream, pos, selpos, nbrp, cntp);
  hipLaunchKernelGGL(mlp_kernel, dim3(NB * NM), dim3(256), 0, stream,
                     x, pos, selpos, nbrp, cntp, w1t, w2t, w3t, b1, b2, b3, out);
}

// Round 4
// 1234.413 us; speedup vs baseline: 1.3369x; 1.0054x over previous
//
#include <hip/hip_runtime.h>
#include <cstdint>

typedef unsigned long long u64;
typedef unsigned int u32;

#define NB 8
#define NP 4096
#define NK 64
#define NM 1024
#define NF 64
#define NOUT 128
#define R2C 0.04f      // float(0.2*0.2 in double) == 0x3D23D70A
#define CAP 2048
#define FPS_T 256
#define FPS_Q 16

// Exact (non-contracted) squared distance, left-to-right sum, matching XLA's
// elementwise (a-b)**2 then reduce over the size-3 axis.
static __device__ __forceinline__ float sq3(float ax, float ay, float az,
                                            float bx, float by, float bz) {
  float dx = __fsub_rn(ax, bx), dy = __fsub_rn(ay, by), dz = __fsub_rn(az, bz);
  return __fadd_rn(__fadd_rn(__fmul_rn(dx, dx), __fmul_rn(dy, dy)), __fmul_rn(dz, dz));
}

// f32 max with a DPP-shifted copy; bound_ctrl=1 feeds 0.0f (safe: d2 >= 0)
template <int CTRL>
static __device__ __forceinline__ float dpp_maxf(float x) {
  int m = __builtin_amdgcn_update_dpp(0, __float_as_int(x), CTRL, 0xf, 0xf, true);
  return fmaxf(x, __int_as_float(m));
}

static __device__ __forceinline__ u64 umax64(u64 a, u64 b) { return a > b ? a : b; }

// ---- kernel 0: transpose weights into ws (ch-major rows -> uniform s_load) ----
__global__ void prep_weights(const float* __restrict__ W1, const float* __restrict__ W2,
                             const float* __restrict__ W3,
                             float* __restrict__ w1t, float* __restrict__ w2t,
                             float* __restrict__ w3t) {
  int t = blockIdx.x * blockDim.x + threadIdx.x;
  int stride = gridDim.x * blockDim.x;
  for (int idx = t; idx < 64 * 67; idx += stride) {
    int ch = idx / 67, i = idx - ch * 67;
    w1t[idx] = W1[i * 64 + ch];
  }
  for (int idx = t; idx < 64 * 64; idx += stride) {
    int ch = idx >> 6, i = idx & 63;
    w2t[idx] = W2[i * 64 + ch];
  }
  for (int idx = t; idx < 128 * 64; idx += stride) {
    int ch = idx >> 6, i = idx & 63;
    w3t[idx] = W3[i * 128 + ch];
  }
}

// ---- kernel 1: FPS — 4 waves x 16 pts/lane; index-carrying local tree,
//      f32 DPP wave max + ballot, 4-slot u64 exchange, NO global stores in loop ----
__global__ __launch_bounds__(FPS_T) void fps_kernel(const float* __restrict__ pos,
                                                    float* __restrict__ selpos_ws,
                                                    float* __restrict__ out_selpos,
                                                    float* __restrict__ out_selbatch) {
  __shared__ float4 pxyz[NP];   // 64 KB
  __shared__ float4 sel[NM];    // 16 KB: selected positions, flushed at end
  __shared__ u64 red[2][4];
  const int b = blockIdx.x, tid = threadIdx.x;
  const float* pb = pos + (size_t)b * NP * 3;
  for (int i = tid; i < NP; i += FPS_T)
    pxyz[i] = make_float4(pb[i * 3], pb[i * 3 + 1], pb[i * 3 + 2], 0.f);
  for (int m = tid; m < NM; m += FPS_T) out_selbatch[b * NM + m] = (float)b;
  __syncthreads();

  float mx[FPS_Q], my[FPS_Q], mz[FPS_Q], d[FPS_Q];
  const float4 p0 = pxyz[0];
#pragma unroll
  for (int q = 0; q < FPS_Q; q++) {
    const float4 P = pxyz[tid * FPS_Q + q];
    mx[q] = P.x; my[q] = P.y; mz[q] = P.z;
    d[q] = sq3(P.x, P.y, P.z, p0.x, p0.y, p0.z);
  }
  if (tid == 0) sel[0] = p0;
  const int lane = tid & 63, w = tid >> 6;

  for (int m = 1; m < NM; m++) {
    // local argmax over 16 via index-carrying pairwise tree (>= keeps lower q)
    float tv8[8]; int ti8[8];
#pragma unroll
    for (int j = 0; j < 8; j++) {
      bool g = d[2 * j] >= d[2 * j + 1];
      tv8[j] = g ? d[2 * j] : d[2 * j + 1];
      ti8[j] = g ? 2 * j : 2 * j + 1;
    }
    float tv4[4]; int ti4[4];
#pragma unroll
    for (int j = 0; j < 4; j++) {
      bool g = tv8[2 * j] >= tv8[2 * j + 1];
      tv4[j] = g ? tv8[2 * j] : tv8[2 * j + 1];
      ti4[j] = g ? ti8[2 * j] : ti8[2 * j + 1];
    }
    float tv2[2]; int ti2[2];
#pragma unroll
    for (int j = 0; j < 2; j++) {
      bool g = tv4[2 * j] >= tv4[2 * j + 1];
      tv2[j] = g ? tv4[2 * j] : tv4[2 * j + 1];
      ti2[j] = g ? ti4[2 * j] : ti4[2 * j + 1];
    }
    const bool g0 = tv2[0] >= tv2[1];
    const float bd = g0 ? tv2[0] : tv2[1];
    const int bq = g0 ? ti2[0] : ti2[1];

    // wave max (f32): shr1,2,4,8 + bcast15 + bcast31 -> lane 63
    float wm = bd;
    wm = dpp_maxf<0x111>(wm);
    wm = dpp_maxf<0x112>(wm);
    wm = dpp_maxf<0x114>(wm);
    wm = dpp_maxf<0x118>(wm);
    wm = dpp_maxf<0x142>(wm);
    wm = dpp_maxf<0x143>(wm);
    const u32 wbits = (u32)__builtin_amdgcn_readlane(__float_as_int(wm), 63);
    const float wmax = __int_as_float((int)wbits);
    const u64 msk = __ballot(bd == wmax);
    const int fl = (int)__ffsll((long long)msk) - 1;       // lowest lane = lowest idx
    const int gi = __builtin_amdgcn_readlane(tid * FPS_Q + bq, fl);
    if (lane == 0)
      red[m & 1][w] = ((u64)wbits << 32) | (u32)(NP - 1 - gi);
    __syncthreads();
    const u64* rs = red[m & 1];
    const u64 g = umax64(umax64(rs[0], rs[1]), umax64(rs[2], rs[3]));
    const int i = NP - 1 - (int)(u32)g;
    const float4 P = pxyz[i];
    if (tid == 0) sel[m] = P;
#pragma unroll
    for (int q = 0; q < FPS_Q; q++)
      d[q] = fminf(d[q], sq3(mx[q], my[q], mz[q], P.x, P.y, P.z));
  }
  __syncthreads();
  for (int m = tid; m < NM; m += FPS_T) {
    const float4 P = sel[m];
    const int o = (b * NM + m) * 3;
    selpos_ws[o] = P.x; selpos_ws[o + 1] = P.y; selpos_ws[o + 2] = P.z;
    out_selpos[o] = P.x; out_selpos[o + 1] = P.y; out_selpos[o + 2] = P.z;
  }
}

// ---- kernel 2: radius ball query + exact K-smallest selection ----
__global__ __launch_bounds__(256) void ball_kernel(const float* __restrict__ pos,
                                                   const float* __restrict__ selpos_ws,
                                                   int* __restrict__ nbrp,
                                                   int* __restrict__ cntp) {
  __shared__ u64 keys[CAP];
  __shared__ int scnt;
  const int bm = blockIdx.x, tid = threadIdx.x;
  const int b = bm >> 10;  // NM = 1024
  if (tid == 0) scnt = 0;
  __syncthreads();
  const float sx = selpos_ws[bm * 3], sy = selpos_ws[bm * 3 + 1], sz = selpos_ws[bm * 3 + 2];
  const float* pb = pos + (size_t)b * NP * 3;
  for (int i = tid; i < NP; i += 256) {
    float d2 = sq3(sx, sy, sz, pb[i * 3], pb[i * 3 + 1], pb[i * 3 + 2]);
    if (d2 <= R2C) {
      int s = atomicAdd(&scnt, 1);
      if (s < CAP) keys[s] = ((u64)__float_as_uint(d2) << 32) | (u32)i;
    }
  }
  __syncthreads();
  int C = scnt > CAP ? CAP : scnt;
  for (int s = tid; s < C; s += 256) {
    u64 k = keys[s];
    int r = 0;
    for (int j2 = 0; j2 < C; j2++) r += (keys[j2] < k) ? 1 : 0;
    if (r < NK) nbrp[bm * NK + r] = (int)(k & 0xffffffffu);
  }
  if (tid == 0) cntp[bm] = C < NK ? C : NK;
}

// ---- kernel 3: MLP — LDS-staged gather (1x traffic), 4-acc ILP, LDS exchange ----
#define XP 69   // xs row pad: 69 % 32 = 5 (odd) -> conflict-free column reads
#define HP 65
__global__ __launch_bounds__(256) void mlp_kernel(
    const float* __restrict__ x, const float* __restrict__ pos,
    const float* __restrict__ selpos_ws, const int* __restrict__ nbrp,
    const int* __restrict__ cntp, const float* __restrict__ w1t,
    const float* __restrict__ w2t, const float* __restrict__ w3t,
    const float* __restrict__ b1, const float* __restrict__ b2,
    const float* __restrict__ b3, float* __restrict__ out) {
  // arena: xs=[64][69] @0 (4416); h1=[64][65] @4416; h2=[64][65] @0; h3=[128][65] @0
  __shared__ float arena[64 * XP + 64 * HP];
  float* xs = arena;
  float* h1s = arena + 64 * XP;
  float* h2s = arena;
  float* h3s = arena;
  const int pm = blockIdx.x, tid = threadIdx.x;
  const int n = tid & 63;
  const int w = __builtin_amdgcn_readfirstlane(tid >> 6);
  const int b = pm >> 10;
  const int c = cntp[pm];
  const float NEGINF = -__builtin_inff();

  // cooperative gather: thread t stages quarter (t&3) of row (t>>2)
  {
    const int r = tid >> 2, p = tid & 3;
    const int jr = (r < c) ? nbrp[pm * NK + r] : 0;
    const float* xr = x + ((size_t)b * NP + jr) * NF + p * 16;
#pragma unroll
    for (int f = 0; f < 4; f++) {
      const float4 v = *(const float4*)(xr + f * 4);
      float* dst = xs + r * XP + p * 16 + f * 4;
      dst[0] = v.x; dst[1] = v.y; dst[2] = v.z; dst[3] = v.w;
    }
    if (p == 0) {
      const float* pr = pos + ((size_t)b * NP + jr) * 3;
      xs[r * XP + 64] = pr[0] - selpos_ws[pm * 3];
      xs[r * XP + 65] = pr[1] - selpos_ws[pm * 3 + 1];
      xs[r * XP + 66] = pr[2] - selpos_ws[pm * 3 + 2];
    }
  }
  __syncthreads();
  float h0[67];
#pragma unroll
  for (int i = 0; i < 67; ++i) h0[i] = xs[n * XP + i];
  // layer 1: 16 channels per wave, 4-acc ILP
  const int cb1 = w * 16;
#pragma unroll
  for (int g = 0; g < 4; ++g) {
    const int ch = cb1 + g * 4;
    float a0 = b1[ch], a1 = b1[ch + 1], a2 = b1[ch + 2], a3 = b1[ch + 3];
    const float* w0 = w1t + ch * 67;
    const float* w1 = w0 + 67;
    const float* w2 = w1 + 67;
    const float* w3 = w2 + 67;
#pragma unroll
    for (int i = 0; i < 67; ++i) {
      const float h = h0[i];
      a0 = fmaf(h, w0[i], a0); a1 = fmaf(h, w1[i], a1);
      a2 = fmaf(h, w2[i], a2); a3 = fmaf(h, w3[i], a3);
    }
    h1s[n * HP + ch] = fmaxf(a0, 0.f);
    h1s[n * HP + ch + 1] = fmaxf(a1, 0.f);
    h1s[n * HP + ch + 2] = fmaxf(a2, 0.f);
    h1s[n * HP + ch + 3] = fmaxf(a3, 0.f);
  }
  __syncthreads();
  float h1r[64];
#pragma unroll
  for (int i = 0; i < 64; ++i) h1r[i] = h1s[n * HP + i];
  // layer 2
#pragma unroll
  for (int g = 0; g < 4; ++g) {
    const int ch = cb1 + g * 4;
    float a0 = b2[ch], a1 = b2[ch + 1], a2 = b2[ch + 2], a3 = b2[ch + 3];
    const float* w0 = w2t + ch * 64;
    const float* w1 = w0 + 64;
    const float* w2 = w1 + 64;
    const float* w3 = w2 + 64;
#pragma unroll
    for (int i = 0; i < 64; ++i) {
      const float h = h1r[i];
      a0 = fmaf(h, w0[i], a0); a1 = fmaf(h, w1[i], a1);
      a2 = fmaf(h, w2[i], a2); a3 = fmaf(h, w3[i], a3);
    }
    h2s[n * HP + ch] = fmaxf(a0, 0.f);
    h2s[n * HP + ch + 1] = fmaxf(a1, 0.f);
    h2s[n * HP + ch + 2] = fmaxf(a2, 0.f);
    h2s[n * HP + ch + 3] = fmaxf(a3, 0.f);
  }
  __syncthreads();
  float h2r[64];
#pragma unroll
  for (int i = 0; i < 64; ++i) h2r[i] = h2s[n * HP + i];
  __syncthreads();  // all h2 reads done before h3 overwrites arena
  // layer 3: 32 channels per wave -> h3[ch][n]
  const bool valid = n < c;
  const int cb3 = w * 32;
#pragma unroll
  for (int g = 0; g < 8; ++g) {
    const int ch = cb3 + g * 4;
    float a0 = b3[ch], a1 = b3[ch + 1], a2 = b3[ch + 2], a3 = b3[ch + 3];
    const float* w0 = w3t + ch * 64;
    const float* w1 = w0 + 64;
    const float* w2 = w1 + 64;
    const float* w3 = w2 + 64;
#pragma unroll
    for (int i = 0; i < 64; ++i) {
      const float h = h2r[i];
      a0 = fmaf(h, w0[i], a0); a1 = fmaf(h, w1[i], a1);
      a2 = fmaf(h, w2[i], a2); a3 = fmaf(h, w3[i], a3);
    }
    h3s[(ch) * HP + n] = valid ? fmaxf(a0, 0.f) : NEGINF;
    h3s[(ch + 1) * HP + n] = valid ? fmaxf(a1, 0.f) : NEGINF;
    h3s[(ch + 2) * HP + n] = valid ? fmaxf(a2, 0.f) : NEGINF;
    h3s[(ch + 3) * HP + n] = valid ? fmaxf(a3, 0.f) : NEGINF;
  }
  __syncthreads();
  if (tid < 128) {
    float m0 = NEGINF;
#pragma unroll
    for (int i = 0; i < 64; ++i) m0 = fmaxf(m0, h3s[tid * HP + i]);
    out[(size_t)pm * NOUT + tid] = (c == 0) ? 0.f : m0;
  }
}

extern "C" void kernel_launch(void* const* d_in, const int* in_sizes, int n_in,
                              void* d_out, int out_size, void* d_ws, size_t ws_size,
                              hipStream_t stream) {
  const float* x   = (const float*)d_in[0];
  const float* pos = (const float*)d_in[1];
  const float* W1 = (const float*)d_in[3];
  const float* b1 = (const float*)d_in[4];
  const float* W2 = (const float*)d_in[5];
  const float* b2 = (const float*)d_in[6];
  const float* W3 = (const float*)d_in[7];
  const float* b3 = (const float*)d_in[8];

  float* out          = (float*)d_out;
  float* out_selpos   = out + (size_t)NB * NM * NOUT;
  float* out_selbatch = out_selpos + (size_t)NB * NM * 3;

  int* ws_i = (int*)d_ws;
  float* ws_f = (float*)d_ws;
  int* cntp     = ws_i + 8192;
  int* nbrp     = ws_i + 16384;
  float* selpos = ws_f + 540672;
  float* w1t    = ws_f + 565248;
  float* w2t    = ws_f + 569536;
  float* w3t    = ws_f + 573632;

  hipLaunchKernelGGL(prep_weights, dim3(34), dim3(256), 0, stream, W1, W2, W3, w1t, w2t, w3t);
  hipLaunchKernelGGL(fps_kernel, dim3(NB), dim3(FPS_T), 0, stream, pos, selpos, out_selpos, out_selbatch);
  hipLaunchKernelGGL(ball_kernel, dim3(NB * NM), dim3(256), 0, stream, pos, selpos, nbrp, cntp);
  hipLaunchKernelGGL(mlp_kernel, dim3(NB * NM), dim3(256), 0, stream,
                     x, pos, selpos, nbrp, cntp, w1t, w2t, w3t, b1, b2, b3, out);
}

// Round 6
// 1136.694 us; speedup vs baseline: 1.4518x; 1.0860x over previous
//
#include <hip/hip_runtime.h>
#include <cstdint>

typedef unsigned long long u64;
typedef unsigned int u32;
typedef float v2f __attribute__((ext_vector_type(2)));

#define NB 8
#define NP 4096
#define NK 64
#define NM 1024
#define NF 64
#define NOUT 128
#define R2C 0.04f      // float(0.2*0.2 in double) == 0x3D23D70A
#define CAP 2048
#define FPS_T 512
#define FPS_Q 8        // 4 float2 pairs per lane

// Exact (non-contracted) squared distance, left-to-right sum, matching XLA's
// elementwise (a-b)**2 then reduce over the size-3 axis.
static __device__ __forceinline__ float sq3(float ax, float ay, float az,
                                            float bx, float by, float bz) {
  float dx = __fsub_rn(ax, bx), dy = __fsub_rn(ay, by), dz = __fsub_rn(az, bz);
  return __fadd_rn(__fadd_rn(__fmul_rn(dx, dx), __fmul_rn(dy, dy)), __fmul_rn(dz, dz));
}

// f32 max with a DPP-shifted copy; bound_ctrl=1 feeds 0.0f (safe: d2 >= 0)
template <int CTRL>
static __device__ __forceinline__ float dpp_maxf(float x) {
  int m = __builtin_amdgcn_update_dpp(0, __float_as_int(x), CTRL, 0xf, 0xf, true);
  return fmaxf(x, __int_as_float(m));
}

static __device__ __forceinline__ u64 umax64(u64 a, u64 b) { return a > b ? a : b; }

// ---- kernel 0: transpose weights into ws (ch-major rows -> uniform s_load) ----
__global__ void prep_weights(const float* __restrict__ W1, const float* __restrict__ W2,
                             const float* __restrict__ W3,
                             float* __restrict__ w1t, float* __restrict__ w2t,
                             float* __restrict__ w3t) {
  int t = blockIdx.x * blockDim.x + threadIdx.x;
  int stride = gridDim.x * blockDim.x;
  for (int idx = t; idx < 64 * 67; idx += stride) {
    int ch = idx / 67, i = idx - ch * 67;
    w1t[idx] = W1[i * 64 + ch];
  }
  for (int idx = t; idx < 64 * 64; idx += stride) {
    int ch = idx >> 6, i = idx & 63;
    w2t[idx] = W2[i * 64 + ch];
  }
  for (int idx = t; idx < 128 * 64; idx += stride) {
    int ch = idx >> 6, i = idx & 63;
    w3t[idx] = W3[i * 128 + ch];
  }
}

// ---- kernel 1: FPS — 8 waves x 8 pts/lane (2 waves/SIMD hides serial chain),
//      packed-f32 update, f32 DPP wave-max + ballot, 8-slot exchange, end flush ----
__global__ __launch_bounds__(FPS_T) void fps_kernel(const float* __restrict__ pos,
                                                    float* __restrict__ selpos_ws,
                                                    float* __restrict__ out_selpos,
                                                    float* __restrict__ out_selbatch) {
  __shared__ float4 pxyz[NP];   // 64 KB
  __shared__ float4 sel[NM];    // 16 KB, flushed at end
  __shared__ u64 red[2][8];
  const int b = blockIdx.x, tid = threadIdx.x;
  const float* pb = pos + (size_t)b * NP * 3;
  for (int i = tid; i < NP; i += FPS_T)
    pxyz[i] = make_float4(pb[i * 3], pb[i * 3 + 1], pb[i * 3 + 2], 0.f);
  for (int m = tid; m < NM; m += FPS_T) out_selbatch[b * NM + m] = (float)b;
  __syncthreads();

  // per-lane state: 4 float2-pairs of coords and running min-dist
  v2f mx[4], my[4], mz[4], d[4];
  const float4 p0 = pxyz[0];
#pragma unroll
  for (int j = 0; j < 4; j++) {
    const float4 A = pxyz[tid * FPS_Q + 2 * j];
    const float4 B = pxyz[tid * FPS_Q + 2 * j + 1];
    mx[j] = (v2f){A.x, B.x}; my[j] = (v2f){A.y, B.y}; mz[j] = (v2f){A.z, B.z};
    d[j] = (v2f){sq3(A.x, A.y, A.z, p0.x, p0.y, p0.z),
                 sq3(B.x, B.y, B.z, p0.x, p0.y, p0.z)};
  }
  if (tid == 0) sel[0] = p0;
  const int lane = tid & 63, w = tid >> 6;

  for (int m = 1; m < NM; m++) {
    // local argmax over 8 via index-carrying pairwise tree (>= keeps lower q)
    float dv[8];
#pragma unroll
    for (int j = 0; j < 4; j++) { dv[2 * j] = d[j].x; dv[2 * j + 1] = d[j].y; }
    float tv4[4]; int ti4[4];
#pragma unroll
    for (int j = 0; j < 4; j++) {
      bool g = dv[2 * j] >= dv[2 * j + 1];
      tv4[j] = g ? dv[2 * j] : dv[2 * j + 1];
      ti4[j] = g ? 2 * j : 2 * j + 1;
    }
    float tv2[2]; int ti2[2];
#pragma unroll
    for (int j = 0; j < 2; j++) {
      bool g = tv4[2 * j] >= tv4[2 * j + 1];
      tv2[j] = g ? tv4[2 * j] : tv4[2 * j + 1];
      ti2[j] = g ? ti4[2 * j] : ti4[2 * j + 1];
    }
    const bool g0 = tv2[0] >= tv2[1];
    const float bd = g0 ? tv2[0] : tv2[1];
    const int bq = g0 ? ti2[0] : ti2[1];

    // wave max (f32): shr1,2,4,8 + bcast15 + bcast31 -> lane 63
    float wm = bd;
    wm = dpp_maxf<0x111>(wm);
    wm = dpp_maxf<0x112>(wm);
    wm = dpp_maxf<0x114>(wm);
    wm = dpp_maxf<0x118>(wm);
    wm = dpp_maxf<0x142>(wm);
    wm = dpp_maxf<0x143>(wm);
    const u32 wbits = (u32)__builtin_amdgcn_readlane(__float_as_int(wm), 63);
    const float wmax = __int_as_float((int)wbits);
    const u64 msk = __ballot(bd == wmax);
    const int fl = (int)__ffsll((long long)msk) - 1;   // lowest lane = lowest idx
    const int gi = __builtin_amdgcn_readlane(tid * FPS_Q + bq, fl);
    if (lane == 0)
      red[m & 1][w] = ((u64)wbits << 32) | (u32)(NP - 1 - gi);
    __syncthreads();
    const u64* rs = red[m & 1];
    const u64 g = umax64(umax64(umax64(rs[0], rs[1]), umax64(rs[2], rs[3])),
                         umax64(umax64(rs[4], rs[5]), umax64(rs[6], rs[7])));
    const int i = NP - 1 - (int)(u32)g;
    const float4 P = pxyz[i];
    if (tid == 0) sel[m] = P;
    // packed update: v_pk_sub/mul/add, contraction OFF to keep exact rounding
    {
#pragma clang fp contract(off)
      const v2f Px = (v2f){P.x, P.x}, Py = (v2f){P.y, P.y}, Pz = (v2f){P.z, P.z};
#pragma unroll
      for (int j = 0; j < 4; j++) {
        v2f dx = mx[j] - Px, dy = my[j] - Py, dz = mz[j] - Pz;
        v2f s = ((dx * dx) + (dy * dy)) + (dz * dz);
        d[j] = __builtin_elementwise_min(d[j], s);
      }
    }
  }
  __syncthreads();
  for (int m = tid; m < NM; m += FPS_T) {
    const float4 P = sel[m];
    const int o = (b * NM + m) * 3;
    selpos_ws[o] = P.x; selpos_ws[o + 1] = P.y; selpos_ws[o + 2] = P.z;
    out_selpos[o] = P.x; out_selpos[o + 1] = P.y; out_selpos[o + 2] = P.z;
  }
}

// ---- kernel 2: radius ball query + exact K-smallest selection ----
__global__ __launch_bounds__(256) void ball_kernel(const float* __restrict__ pos,
                                                   const float* __restrict__ selpos_ws,
                                                   int* __restrict__ nbrp,
                                                   int* __restrict__ cntp) {
  __shared__ u64 keys[CAP];
  __shared__ int scnt;
  const int bm = blockIdx.x, tid = threadIdx.x;
  const int b = bm >> 10;  // NM = 1024
  if (tid == 0) scnt = 0;
  __syncthreads();
  const float sx = selpos_ws[bm * 3], sy = selpos_ws[bm * 3 + 1], sz = selpos_ws[bm * 3 + 2];
  const float* pb = pos + (size_t)b * NP * 3;
  for (int i = tid; i < NP; i += 256) {
    float d2 = sq3(sx, sy, sz, pb[i * 3], pb[i * 3 + 1], pb[i * 3 + 2]);
    if (d2 <= R2C) {
      int s = atomicAdd(&scnt, 1);
      if (s < CAP) keys[s] = ((u64)__float_as_uint(d2) << 32) | (u32)i;
    }
  }
  __syncthreads();
  int C = scnt > CAP ? CAP : scnt;
  for (int s = tid; s < C; s += 256) {
    u64 k = keys[s];
    int r = 0;
    for (int j2 = 0; j2 < C; j2++) r += (keys[j2] < k) ? 1 : 0;
    if (r < NK) nbrp[bm * NK + r] = (int)(k & 0xffffffffu);
  }
  if (tid == 0) cntp[bm] = C < NK ? C : NK;
}

// ---- kernel 3: MLP — LDS-staged gather (1x traffic), 4-acc ILP, LDS exchange ----
#define XP 69   // xs row pad: 69 % 32 = 5 (odd) -> conflict-free column reads
#define HP 65
__global__ __launch_bounds__(256) void mlp_kernel(
    const float* __restrict__ x, const float* __restrict__ pos,
    const float* __restrict__ selpos_ws, const int* __restrict__ nbrp,
    const int* __restrict__ cntp, const float* __restrict__ w1t,
    const float* __restrict__ w2t, const float* __restrict__ w3t,
    const float* __restrict__ b1, const float* __restrict__ b2,
    const float* __restrict__ b3, float* __restrict__ out) {
  __shared__ float arena[64 * XP + 64 * HP];
  float* xs = arena;
  float* h1s = arena + 64 * XP;
  float* h2s = arena;
  float* h3s = arena;
  const int pm = blockIdx.x, tid = threadIdx.x;
  const int n = tid & 63;
  const int w = __builtin_amdgcn_readfirstlane(tid >> 6);
  const int b = pm >> 10;
  const int c = cntp[pm];
  const float NEGINF = -__builtin_inff();

  {
    const int r = tid >> 2, p = tid & 3;
    const int jr = (r < c) ? nbrp[pm * NK + r] : 0;
    const float* xr = x + ((size_t)b * NP + jr) * NF + p * 16;
#pragma unroll
    for (int f = 0; f < 4; f++) {
      const float4 v = *(const float4*)(xr + f * 4);
      float* dst = xs + r * XP + p * 16 + f * 4;
      dst[0] = v.x; dst[1] = v.y; dst[2] = v.z; dst[3] = v.w;
    }
    if (p == 0) {
      const float* pr = pos + ((size_t)b * NP + jr) * 3;
      xs[r * XP + 64] = pr[0] - selpos_ws[pm * 3];
      xs[r * XP + 65] = pr[1] - selpos_ws[pm * 3 + 1];
      xs[r * XP + 66] = pr[2] - selpos_ws[pm * 3 + 2];
    }
  }
  __syncthreads();
  float h0[67];
#pragma unroll
  for (int i = 0; i < 67; ++i) h0[i] = xs[n * XP + i];
  const int cb1 = w * 16;
#pragma unroll
  for (int g = 0; g < 4; ++g) {
    const int ch = cb1 + g * 4;
    float a0 = b1[ch], a1 = b1[ch + 1], a2 = b1[ch + 2], a3 = b1[ch + 3];
    const float* w0 = w1t + ch * 67;
    const float* w1 = w0 + 67;
    const float* w2 = w1 + 67;
    const float* w3 = w2 + 67;
#pragma unroll
    for (int i = 0; i < 67; ++i) {
      const float h = h0[i];
      a0 = fmaf(h, w0[i], a0); a1 = fmaf(h, w1[i], a1);
      a2 = fmaf(h, w2[i], a2); a3 = fmaf(h, w3[i], a3);
    }
    h1s[n * HP + ch] = fmaxf(a0, 0.f);
    h1s[n * HP + ch + 1] = fmaxf(a1, 0.f);
    h1s[n * HP + ch + 2] = fmaxf(a2, 0.f);
    h1s[n * HP + ch + 3] = fmaxf(a3, 0.f);
  }
  __syncthreads();
  float h1r[64];
#pragma unroll
  for (int i = 0; i < 64; ++i) h1r[i] = h1s[n * HP + i];
#pragma unroll
  for (int g = 0; g < 4; ++g) {
    const int ch = cb1 + g * 4;
    float a0 = b2[ch], a1 = b2[ch + 1], a2 = b2[ch + 2], a3 = b2[ch + 3];
    const float* w0 = w2t + ch * 64;
    const float* w1 = w0 + 64;
    const float* w2 = w1 + 64;
    const float* w3 = w2 + 64;
#pragma unroll
    for (int i = 0; i < 64; ++i) {
      const float h = h1r[i];
      a0 = fmaf(h, w0[i], a0); a1 = fmaf(h, w1[i], a1);
      a2 = fmaf(h, w2[i], a2); a3 = fmaf(h, w3[i], a3);
    }
    h2s[n * HP + ch] = fmaxf(a0, 0.f);
    h2s[n * HP + ch + 1] = fmaxf(a1, 0.f);
    h2s[n * HP + ch + 2] = fmaxf(a2, 0.f);
    h2s[n * HP + ch + 3] = fmaxf(a3, 0.f);
  }
  __syncthreads();
  float h2r[64];
#pragma unroll
  for (int i = 0; i < 64; ++i) h2r[i] = h2s[n * HP + i];
  __syncthreads();
  const bool valid = n < c;
  const int cb3 = w * 32;
#pragma unroll
  for (int g = 0; g < 8; ++g) {
    const int ch = cb3 + g * 4;
    float a0 = b3[ch], a1 = b3[ch + 1], a2 = b3[ch + 2], a3 = b3[ch + 3];
    const float* w0 = w3t + ch * 64;
    const float* w1 = w0 + 64;
    const float* w2 = w1 + 64;
    const float* w3 = w2 + 64;
#pragma unroll
    for (int i = 0; i < 64; ++i) {
      const float h = h2r[i];
      a0 = fmaf(h, w0[i], a0); a1 = fmaf(h, w1[i], a1);
      a2 = fmaf(h, w2[i], a2); a3 = fmaf(h, w3[i], a3);
    }
    h3s[(ch) * HP + n] = valid ? fmaxf(a0, 0.f) : NEGINF;
    h3s[(ch + 1) * HP + n] = valid ? fmaxf(a1, 0.f) : NEGINF;
    h3s[(ch + 2) * HP + n] = valid ? fmaxf(a2, 0.f) : NEGINF;
    h3s[(ch + 3) * HP + n] = valid ? fmaxf(a3, 0.f) : NEGINF;
  }
  __syncthreads();
  if (tid < 128) {
    float m0 = NEGINF;
#pragma unroll
    for (int i = 0; i < 64; ++i) m0 = fmaxf(m0, h3s[tid * HP + i]);
    out[(size_t)pm * NOUT + tid] = (c == 0) ? 0.f : m0;
  }
}

extern "C" void kernel_launch(void* const* d_in, const int* in_sizes, int n_in,
                              void* d_out, int out_size, void* d_ws, size_t ws_size,
                              hipStream_t stream) {
  const float* x   = (const float*)d_in[0];
  const float* pos = (const float*)d_in[1];
  const float* W1 = (const float*)d_in[3];
  const float* b1 = (const float*)d_in[4];
  const float* W2 = (const float*)d_in[5];
  const float* b2 = (const float*)d_in[6];
  const float* W3 = (const float*)d_in[7];
  const float* b3 = (const float*)d_in[8];

  float* out          = (float*)d_out;
  float* out_selpos   = out + (size_t)NB * NM * NOUT;
  float* out_selbatch = out_selpos + (size_t)NB * NM * 3;

  int* ws_i = (int*)d_ws;
  float* ws_f = (float*)d_ws;
  int* cntp     = ws_i + 8192;
  int* nbrp     = ws_i + 16384;
  float* selpos = ws_f + 540672;
  float* w1t    = ws_f + 565248;
  float* w2t    = ws_f + 569536;
  float* w3t    = ws_f + 573632;

  hipLaunchKernelGGL(prep_weights, dim3(34), dim3(256), 0, stream, W1, W2, W3, w1t, w2t, w3t);
  hipLaunchKernelGGL(fps_kernel, dim3(NB), dim3(FPS_T), 0, stream, pos, selpos, out_selpos, out_selbatch);
  hipLaunchKernelGGL(ball_kernel, dim3(NB * NM), dim3(256), 0, stream, pos, selpos, nbrp, cntp);
  hipLaunchKernelGGL(mlp_kernel, dim3(NB * NM), dim3(256), 0, stream,
                     x, pos, selpos, nbrp, cntp, w1t, w2t, w3t, b1, b2, b3, out);
}